// Round 1
// baseline (532.567 us; speedup 1.0000x reference)
//
#include <hip/hip_runtime.h>
#include <hip/hip_bf16.h>
#include <stdint.h>

// Problem constants (B, C, H, W, K) = (16, 64, 192, 192, 3)
#define NB 16
#define NC 64
#define NH 192
#define NW 192
#define NKDIM 576   // 9 taps * 64 ci, tap-major: k = tap*64 + ci

typedef __bf16 bf16x8 __attribute__((ext_vector_type(8)));
typedef __bf16 bf16x2 __attribute__((ext_vector_type(2)));
typedef float  f32x4  __attribute__((ext_vector_type(4)));

static __device__ __forceinline__ __bf16 f2bf(float f) { return (__bf16)f; }

// ---------------------------------------------------------------------------
// Pre-kernel: blend W0/W1 per batch into bf16, layout A[b][co][tap*64+ci].
// Tap-major K ordering means each K=32 MFMA step is a contiguous ci-slice at a
// single (dh,dw) shift -> B operand is a plain slab of x, no im2col.
// ---------------------------------------------------------------------------
__global__ __launch_bounds__(256)
void blend_kernel(const float* __restrict__ W0, const float* __restrict__ W1,
                  const float* __restrict__ DoT, __bf16* __restrict__ A) {
    int idx = blockIdx.x * 256 + threadIdx.x;   // 16*64*576 total, exact grid
    int k   = idx % NKDIM;
    int co  = (idx / NKDIM) % NC;
    int b   = idx / (NKDIM * NC);
    int tap = k >> 6;
    int ci  = k & 63;
    float d  = DoT[b];
    int wi   = (co * NC + ci) * 9 + tap;
    float v  = (1.0f - d) * W0[wi] + d * W1[wi];
    A[idx] = f2bf(v);
}

// ---------------------------------------------------------------------------
// Implicit-GEMM conv. Block = 256 thr (4 waves) -> 64 co x (2 rows x 64 w).
// LDS: x slab rows h0-1..h0+2, w0-1..w0+64, ci-contiguous (pad 72 keeps every
// [w][ci0] frag base 16B-aligned -> ds_read_b128).
// Wave w: mh = w&1 (co half), nh = w>>1 (row half). Per K-step: 2 A-frags
// (global, L2-hot 72KB/batch) + 4 B-frags (LDS) + 8 MFMA 16x16x32_bf16.
// ---------------------------------------------------------------------------
__global__ __launch_bounds__(256)
void conv_kernel(const float* __restrict__ x, const __bf16* __restrict__ A,
                 float* __restrict__ out) {
    __shared__ __bf16 xs[4][66][72];   // [row][w+halo][ci padded] = 38016 B

    const int b  = blockIdx.z;
    const int h0 = blockIdx.y * 2;
    const int w0 = blockIdx.x * 64;

    const int tid  = threadIdx.x;
    const int lane = tid & 63;
    const int wave = tid >> 6;

    // ---- stage x slab: each wave stages one input row (r = wave) ----
    {
        const float* xb = x + (size_t)b * NC * NH * NW;
        const int r  = wave;
        const int gr = h0 - 1 + r;
        const bool rowok = (gr >= 0) && (gr < NH);
        const int gw  = w0 - 1 + lane;            // main 64 columns
        const bool wok  = rowok && (gw >= 0);     // gw < NW always holds here
        const int gw2 = w0 + 63 + lane;           // 2 halo columns (lane<2)
        const bool w2ok = rowok && (gw2 < NW);
        for (int i = 0; i < 32; ++i) {
            const int ci = i * 2;
            const float* p0 = xb + ((size_t)ci * NH + gr) * NW;
            const float* p1 = p0 + (size_t)NH * NW;
            float v0 = wok ? p0[gw] : 0.0f;
            float v1 = wok ? p1[gw] : 0.0f;
            bf16x2 pk = { f2bf(v0), f2bf(v1) };
            *(bf16x2*)&xs[r][lane][ci] = pk;
            if (lane < 2) {
                float u0 = w2ok ? p0[gw2] : 0.0f;
                float u1 = w2ok ? p1[gw2] : 0.0f;
                bf16x2 pk2 = { f2bf(u0), f2bf(u1) };
                *(bf16x2*)&xs[r][64 + lane][ci] = pk2;
            }
        }
    }
    __syncthreads();

    // ---- MFMA main loop ----
    const int mh   = wave & 1;    // co half: 0 -> co 0..31, 1 -> co 32..63
    const int nh   = wave >> 1;   // local output row 0/1
    const int n    = lane & 15;
    const int quad = lane >> 4;

    // A fragment rows for this lane (A[m=lane&15][k=quad*8+j], m89-verified)
    const __bf16* A0 = A + ((size_t)b * NC + mh * 32 + n) * NKDIM + quad * 8;
    const __bf16* A1 = A0 + (size_t)16 * NKDIM;

    f32x4 acc[2][4] = {};   // [co tile][w tile], 32 VGPRs

    for (int tap = 0; tap < 9; ++tap) {
        const int dh = tap / 3;
        const int dw = tap - dh * 3;
        // B operand base: xs[nh+dh][dw + n + nt*16][ci]
        const __bf16* xrow = &xs[nh + dh][dw + n][0];
        #pragma unroll
        for (int ch = 0; ch < 2; ++ch) {
            bf16x8 a0 = *(const bf16x8*)(A0 + tap * 64 + ch * 32);
            bf16x8 a1 = *(const bf16x8*)(A1 + tap * 64 + ch * 32);
            const int cb = ch * 32 + quad * 8;
            #pragma unroll
            for (int nt = 0; nt < 4; ++nt) {
                bf16x8 bf = *(const bf16x8*)(xrow + nt * 16 * 72 + cb);
                acc[0][nt] = __builtin_amdgcn_mfma_f32_16x16x32_bf16(
                    a0, bf, acc[0][nt], 0, 0, 0);
                acc[1][nt] = __builtin_amdgcn_mfma_f32_16x16x32_bf16(
                    a1, bf, acc[1][nt], 0, 0, 0);
            }
        }
    }

    // ---- epilogue: D col=lane&15 (w), row=quad*4+reg (co) ----
    const int h = h0 + nh;
    float* ob = out + (size_t)b * NC * NH * NW + (size_t)h * NW + w0;
    #pragma unroll
    for (int mt = 0; mt < 2; ++mt) {
        const int cobase = mh * 32 + mt * 16 + quad * 4;
        #pragma unroll
        for (int reg = 0; reg < 4; ++reg) {
            float* orow = ob + (size_t)(cobase + reg) * NH * NW;
            #pragma unroll
            for (int nt = 0; nt < 4; ++nt) {
                orow[nt * 16 + n] = acc[mt][nt][reg];
            }
        }
    }
}

// ---------------------------------------------------------------------------
extern "C" void kernel_launch(void* const* d_in, const int* in_sizes, int n_in,
                              void* d_out, int out_size, void* d_ws, size_t ws_size,
                              hipStream_t stream) {
    const float* x   = (const float*)d_in[0];
    const float* DoT = (const float*)d_in[1];
    const float* W0  = (const float*)d_in[2];
    const float* W1  = (const float*)d_in[3];
    float* out = (float*)d_out;

    // Workspace: blended bf16 kernel, 16*64*576*2 = 1,179,648 bytes.
    __bf16* A = (__bf16*)d_ws;

    blend_kernel<<<dim3((NB * NC * NKDIM) / 256), 256, 0, stream>>>(W0, W1, DoT, A);
    conv_kernel<<<dim3(NW / 64, NH / 2, NB), dim3(256), 0, stream>>>(x, A, out);
}

// Round 2
// 447.445 us; speedup vs baseline: 1.1902x; 1.1902x over previous
//
#include <hip/hip_runtime.h>
#include <hip/hip_bf16.h>
#include <stdint.h>

// Problem constants (B, C, H, W, K) = (16, 64, 192, 192, 3)
#define NB 16
#define NC 64
#define NH 192
#define NW 192
#define NKDIM 576   // 9 taps * 64 ci, tap-major: k = tap*64 + ci

typedef __bf16 bf16x8 __attribute__((ext_vector_type(8)));
typedef __bf16 bf16x4 __attribute__((ext_vector_type(4)));
typedef float  f32x4  __attribute__((ext_vector_type(4)));

static __device__ __forceinline__ __bf16 f2bf(float f) { return (__bf16)f; }

// ---------------------------------------------------------------------------
// Pre-kernel: blend W0/W1 per batch into bf16, layout A[b][co][tap*64+ci].
// ---------------------------------------------------------------------------
__global__ __launch_bounds__(256)
void blend_kernel(const float* __restrict__ W0, const float* __restrict__ W1,
                  const float* __restrict__ DoT, __bf16* __restrict__ A) {
    int idx = blockIdx.x * 256 + threadIdx.x;   // 16*64*576 total, exact grid
    int k   = idx % NKDIM;
    int co  = (idx / NKDIM) % NC;
    int b   = idx / (NKDIM * NC);
    int tap = k >> 6;
    int ci  = k & 63;
    float d  = DoT[b];
    int wi   = (co * NC + ci) * 9 + tap;
    float v  = (1.0f - d) * W0[wi] + d * W1[wi];
    A[idx] = f2bf(v);
}

// ---------------------------------------------------------------------------
// Implicit-GEMM conv. Block = 512 thr (8 waves) -> 64 co x (2 rows x 64 w).
// wave: mt = wave&3 (16-co tile), nh = wave>>2 (output row 0/1).
// A fully register-resident per wave (18 x bf16x8 = 72 VGPR) -> main loop is
// pure ds_read_b128 + MFMA, no global deps.
// LDS xs[4][66][72] bf16 (stride 144B, 16B-aligned). ci stored in 16B groups
// of 8, group-index XOR-swizzled with (w>>3): staging b64 writes conflict-free
// (8 colliding w-lanes -> 8 distinct groups), b128 reads <=2-way (free).
// ---------------------------------------------------------------------------
__global__ __launch_bounds__(512, 4)
void conv_kernel(const float* __restrict__ x, const __bf16* __restrict__ A,
                 float* __restrict__ out) {
    __shared__ __bf16 xs[4 * 66 * 72];   // 38016 B

    const int b  = blockIdx.z;
    const int h0 = blockIdx.y * 2;
    const int w0 = blockIdx.x * 64;

    const int tid  = threadIdx.x;
    const int lane = tid & 63;
    const int wave = tid >> 6;

    // ---- stage x slab: 4 rows x 66 w x 64 ci -> bf16 LDS ----
    {
        const int r  = tid >> 7;      // input row 0..3 (2 waves per row)
        const int s  = tid & 127;
        const int gr = h0 - 1 + r;
        const bool rowok = (gr >= 0) && (gr < NH);
        const float* xb = x + (size_t)b * NC * NH * NW + (ptrdiff_t)gr * NW;

        #pragma unroll
        for (int j = 0; j < 8; ++j) {
            const int p   = j * 128 + s;
            const int wl  = p & 63;          // LDS w index 0..63
            const int ci4 = p >> 6;          // 0..15 (4 ci per thread)
            const int gw  = w0 - 1 + wl;     // global w (may be -1)
            const bool ok = rowok && (gw >= 0);
            float v0 = ok ? xb[(size_t)(ci4 * 4 + 0) * NH * NW + gw] : 0.0f;
            float v1 = ok ? xb[(size_t)(ci4 * 4 + 1) * NH * NW + gw] : 0.0f;
            float v2 = ok ? xb[(size_t)(ci4 * 4 + 2) * NH * NW + gw] : 0.0f;
            float v3 = ok ? xb[(size_t)(ci4 * 4 + 3) * NH * NW + gw] : 0.0f;
            bf16x4 pk = { f2bf(v0), f2bf(v1), f2bf(v2), f2bf(v3) };
            const int g  = ci4 >> 1;
            const int gp = g ^ ((wl >> 3) & 7);
            *(bf16x4*)&xs[(r * 66 + wl) * 72 + gp * 8 + (ci4 & 1) * 4] = pk;
        }
        // halo columns wl = 64, 65 (gw = w0+63, w0+64)
        if (s < 32) {
            const int wl  = 64 + (s & 1);
            const int ci4 = s >> 1;
            const int gw  = w0 - 1 + wl;
            const bool ok = rowok && (gw < NW);
            float v0 = ok ? xb[(size_t)(ci4 * 4 + 0) * NH * NW + gw] : 0.0f;
            float v1 = ok ? xb[(size_t)(ci4 * 4 + 1) * NH * NW + gw] : 0.0f;
            float v2 = ok ? xb[(size_t)(ci4 * 4 + 2) * NH * NW + gw] : 0.0f;
            float v3 = ok ? xb[(size_t)(ci4 * 4 + 3) * NH * NW + gw] : 0.0f;
            bf16x4 pk = { f2bf(v0), f2bf(v1), f2bf(v2), f2bf(v3) };
            const int g  = ci4 >> 1;
            const int gp = g ^ ((wl >> 3) & 7);
            *(bf16x4*)&xs[(r * 66 + wl) * 72 + gp * 8 + (ci4 & 1) * 4] = pk;
        }
    }

    // ---- A prefetch: whole wave's weights into registers (L2-hot) ----
    const int mt   = wave & 3;    // co tile: co = mt*16 .. +16
    const int nh   = wave >> 2;   // output row 0/1
    const int n    = lane & 15;
    const int quad = lane >> 4;

    // A[m=lane&15][k=quad*8+j] layout (m89-verified), k = tap*64 + ch*32 + quad*8 + j
    const __bf16* Ap = A + ((size_t)b * NC + mt * 16 + n) * NKDIM + quad * 8;
    bf16x8 afr[9][2];
    #pragma unroll
    for (int tap = 0; tap < 9; ++tap)
        #pragma unroll
        for (int ch = 0; ch < 2; ++ch)
            afr[tap][ch] = *(const bf16x8*)(Ap + tap * 64 + ch * 32);

    __syncthreads();

    // ---- MFMA main loop: 9 taps x 2 ch x 4 nt = 72 MFMA per wave ----
    f32x4 acc[4];
    #pragma unroll
    for (int nt = 0; nt < 4; ++nt) acc[nt] = (f32x4){0.f, 0.f, 0.f, 0.f};

    #pragma unroll
    for (int tap = 0; tap < 9; ++tap) {
        const int dh  = tap / 3;
        const int dw  = tap - dh * 3;
        const int row = nh + dh;
        #pragma unroll
        for (int ch = 0; ch < 2; ++ch) {
            const int g = ch * 4 + quad;
            #pragma unroll
            for (int nt = 0; nt < 4; ++nt) {
                const int wl = dw + nt * 16 + n;
                const int gp = g ^ ((wl >> 3) & 7);
                bf16x8 bfr = *(const bf16x8*)&xs[(row * 66 + wl) * 72 + gp * 8];
                acc[nt] = __builtin_amdgcn_mfma_f32_16x16x32_bf16(
                    afr[tap][ch], bfr, acc[nt], 0, 0, 0);
            }
        }
    }

    // ---- epilogue: D col=lane&15 (w), row=quad*4+reg (co within tile) ----
    const int h = h0 + nh;
    float* ob = out + (size_t)b * NC * NH * NW + (size_t)h * NW + w0;
    #pragma unroll
    for (int reg = 0; reg < 4; ++reg) {
        const int co = mt * 16 + quad * 4 + reg;
        float* orow = ob + (size_t)co * NH * NW;
        #pragma unroll
        for (int nt = 0; nt < 4; ++nt) {
            orow[nt * 16 + n] = acc[nt][reg];
        }
    }
}

// ---------------------------------------------------------------------------
extern "C" void kernel_launch(void* const* d_in, const int* in_sizes, int n_in,
                              void* d_out, int out_size, void* d_ws, size_t ws_size,
                              hipStream_t stream) {
    const float* x   = (const float*)d_in[0];
    const float* DoT = (const float*)d_in[1];
    const float* W0  = (const float*)d_in[2];
    const float* W1  = (const float*)d_in[3];
    float* out = (float*)d_out;

    // Workspace: blended bf16 kernel, 16*64*576*2 = 1,179,648 bytes.
    __bf16* A = (__bf16*)d_ws;

    blend_kernel<<<dim3((NB * NC * NKDIM) / 256), 256, 0, stream>>>(W0, W1, DoT, A);
    conv_kernel<<<dim3(NW / 64, NH / 2, NB), dim3(512), 0, stream>>>(x, A, out);
}

// Round 3
// 372.456 us; speedup vs baseline: 1.4299x; 1.2013x over previous
//
#include <hip/hip_runtime.h>
#include <hip/hip_bf16.h>
#include <stdint.h>

// Problem constants (B, C, H, W, K) = (16, 64, 192, 192, 3)
#define NB 16
#define NC 64
#define NH 192
#define NW 192
#define NKDIM 576   // 9 taps * 64 ci, tap-major: k = tap*64 + ci

typedef __bf16 bf16x8 __attribute__((ext_vector_type(8)));
typedef __bf16 bf16x4 __attribute__((ext_vector_type(4)));
typedef float  f32x4  __attribute__((ext_vector_type(4)));

static __device__ __forceinline__ __bf16 f2bf(float f) { return (__bf16)f; }

// ---------------------------------------------------------------------------
// Blend W0/W1 per batch into bf16, layout A[b][co][tap*64+ci] (tap-major K).
// ---------------------------------------------------------------------------
__global__ __launch_bounds__(256)
void blend_kernel(const float* __restrict__ W0, const float* __restrict__ W1,
                  const float* __restrict__ DoT, __bf16* __restrict__ A) {
    int idx = blockIdx.x * 256 + threadIdx.x;   // 16*64*576 total, exact grid
    int k   = idx % NKDIM;
    int co  = (idx / NKDIM) % NC;
    int b   = idx / (NKDIM * NC);
    int tap = k >> 6;
    int ci  = k & 63;
    float d  = DoT[b];
    int wi   = (co * NC + ci) * 9 + tap;
    float v  = (1.0f - d) * W0[wi] + d * W1[wi];
    A[idx] = f2bf(v);
}

// ---------------------------------------------------------------------------
// Pass 1: x NCHW fp32 -> xt NHWC bf16.  Block = 256 thr, tile = 64 ci x 64 w
// for one (b,h).  LDS fp32 tile [w][ci] stride 68 (16B-aligned, bank-uniform).
// ---------------------------------------------------------------------------
__global__ __launch_bounds__(256)
void nhwc_cvt_kernel(const float* __restrict__ x, __bf16* __restrict__ xt) {
    __shared__ float tile[64 * 68];   // 17408 B

    const int b  = blockIdx.z;
    const int h  = blockIdx.y;
    const int wt = blockIdx.x * 64;
    const int t  = threadIdx.x;

    // read phase: thread (ci = t&63, wq = t>>6) loads 4 float4 along w
    {
        const int ci = t & 63;
        const int wq = t >> 6;
        const float* src = x + ((size_t)(b * NC + ci) * NH + h) * NW + wt;
        #pragma unroll
        for (int w4l = 0; w4l < 4; ++w4l) {
            const int w4 = wq * 4 + w4l;
            f32x4 v = *(const f32x4*)(src + w4 * 4);
            #pragma unroll
            for (int j = 0; j < 4; ++j)
                tile[(w4 * 4 + j) * 68 + ci] = v[j];
        }
    }
    __syncthreads();

    // write phase: chunk c -> (w = c>>3, cig = c&7); 8 ci -> bf16x8 store
    __bf16* dst = xt + ((size_t)(b * NH + h) * NW + wt) * NC;
    #pragma unroll
    for (int it = 0; it < 2; ++it) {
        const int c   = it * 256 + t;
        const int w   = c >> 3;
        const int cig = c & 7;
        f32x4 v0 = *(const f32x4*)&tile[w * 68 + cig * 8];
        f32x4 v1 = *(const f32x4*)&tile[w * 68 + cig * 8 + 4];
        bf16x8 pk = { f2bf(v0[0]), f2bf(v0[1]), f2bf(v0[2]), f2bf(v0[3]),
                      f2bf(v1[0]), f2bf(v1[1]), f2bf(v1[2]), f2bf(v1[3]) };
        *(bf16x8*)(dst + (size_t)w * NC + cig * 8) = pk;
    }
}

// ---------------------------------------------------------------------------
// Pass 2: implicit-GEMM conv from NHWC bf16.  Block = 512 thr (8 waves) ->
// 64 co x (2 rows x 64 w).  wave: mt = wave&3 (16-co tile), nh = wave>>2.
// LDS xs[r][w][g'][8] bf16, g' = g ^ (w&7): both ds_write_b128 (staging) and
// ds_read_b128 (main loop) are exactly bank-uniform -> zero conflicts.
// A register-resident per wave; main loop = pure ds_read_b128 + MFMA.
// ---------------------------------------------------------------------------
__global__ __launch_bounds__(512, 4)
void conv_nhwc_kernel(const __bf16* __restrict__ xt, const __bf16* __restrict__ A,
                      float* __restrict__ out) {
    __shared__ __bf16 xs[4 * 66 * 8 * 8];   // 33792 B

    const int b  = blockIdx.z;
    const int h0 = blockIdx.y * 2;
    const int w0 = blockIdx.x * 64;

    const int tid  = threadIdx.x;
    const int lane = tid & 63;
    const int wave = tid >> 6;

    // ---- stage 4 rows x 66 w x 64 ci (bf16, 16B chunks, swizzled) ----
    // 2112 chunks: chunk c -> r = c/528, w = (c%528)>>3, g = c&7
    {
        #pragma unroll
        for (int it = 0; it < 4; ++it) {
            const int c   = it * 512 + tid;
            const int r   = c / 528;
            const int rem = c - r * 528;
            const int w   = rem >> 3;
            const int g   = rem & 7;
            const int gr  = h0 - 1 + r;
            const int gw  = w0 - 1 + w;
            const bool ok = (gr >= 0) && (gr < NH) && (gw >= 0) && (gw < NW);
            bf16x8 v = {};
            if (ok)
                v = *(const bf16x8*)(xt + ((size_t)(b * NH + gr) * NW + gw) * NC + g * 8);
            *(bf16x8*)&xs[(((r * 66 + w) * 8) + (g ^ (w & 7))) * 8] = v;
        }
        if (tid < 64) {
            const int c   = 2048 + tid;
            const int r   = 3;
            const int rem = c - 3 * 528;
            const int w   = rem >> 3;
            const int g   = rem & 7;
            const int gr  = h0 + 2;
            const int gw  = w0 - 1 + w;
            const bool ok = (gr < NH) && (gw < NW);   // gr>=0, gw>=0 hold here
            bf16x8 v = {};
            if (ok)
                v = *(const bf16x8*)(xt + ((size_t)(b * NH + gr) * NW + gw) * NC + g * 8);
            *(bf16x8*)&xs[(((r * 66 + w) * 8) + (g ^ (w & 7))) * 8] = v;
        }
    }

    // ---- A prefetch: whole wave's weights into registers (L2-hot) ----
    const int mt   = wave & 3;    // co tile: co = mt*16 .. +16
    const int nh   = wave >> 2;   // output row 0/1
    const int n    = lane & 15;
    const int quad = lane >> 4;

    // A[m=lane&15][k=quad*8+j] (m89-verified), k = tap*64 + ch*32 + quad*8 + j
    const __bf16* Ap = A + ((size_t)b * NC + mt * 16 + n) * NKDIM + quad * 8;
    bf16x8 afr[9][2];
    #pragma unroll
    for (int tap = 0; tap < 9; ++tap)
        #pragma unroll
        for (int ch = 0; ch < 2; ++ch)
            afr[tap][ch] = *(const bf16x8*)(Ap + tap * 64 + ch * 32);

    __syncthreads();

    // ---- MFMA main loop: 9 taps x 2 ch x 4 nt = 72 MFMA per wave ----
    f32x4 acc[4];
    #pragma unroll
    for (int nt = 0; nt < 4; ++nt) acc[nt] = (f32x4){0.f, 0.f, 0.f, 0.f};

    #pragma unroll
    for (int tap = 0; tap < 9; ++tap) {
        const int dh  = tap / 3;
        const int dw  = tap - dh * 3;
        const int row = nh + dh;
        #pragma unroll
        for (int ch = 0; ch < 2; ++ch) {
            #pragma unroll
            for (int nt = 0; nt < 4; ++nt) {
                const int wl = dw + nt * 16 + n;
                const int gp = (ch * 4 + quad) ^ (wl & 7);
                bf16x8 bfr = *(const bf16x8*)&xs[(((row * 66 + wl) * 8) + gp) * 8];
                acc[nt] = __builtin_amdgcn_mfma_f32_16x16x32_bf16(
                    afr[tap][ch], bfr, acc[nt], 0, 0, 0);
            }
        }
    }

    // ---- epilogue: D col=lane&15 (w), row=quad*4+reg (co within tile) ----
    const int h = h0 + nh;
    float* ob = out + (size_t)b * NC * NH * NW + (size_t)h * NW + w0;
    #pragma unroll
    for (int reg = 0; reg < 4; ++reg) {
        const int co = mt * 16 + quad * 4 + reg;
        float* orow = ob + (size_t)co * NH * NW;
        #pragma unroll
        for (int nt = 0; nt < 4; ++nt) {
            orow[nt * 16 + n] = acc[nt][reg];
        }
    }
}

// ---------------------------------------------------------------------------
// Fallback (round-2 single-pass NCHW kernel) if ws_size is too small for xt.
// ---------------------------------------------------------------------------
__global__ __launch_bounds__(512, 4)
void conv_nchw_kernel(const float* __restrict__ x, const __bf16* __restrict__ A,
                      float* __restrict__ out) {
    __shared__ __bf16 xs[4 * 66 * 72];

    const int b  = blockIdx.z;
    const int h0 = blockIdx.y * 2;
    const int w0 = blockIdx.x * 64;

    const int tid  = threadIdx.x;
    const int lane = tid & 63;
    const int wave = tid >> 6;

    {
        const int r  = tid >> 7;
        const int s  = tid & 127;
        const int gr = h0 - 1 + r;
        const bool rowok = (gr >= 0) && (gr < NH);
        const float* xb = x + (size_t)b * NC * NH * NW + (ptrdiff_t)gr * NW;

        #pragma unroll
        for (int j = 0; j < 8; ++j) {
            const int p   = j * 128 + s;
            const int wl  = p & 63;
            const int ci4 = p >> 6;
            const int gw  = w0 - 1 + wl;
            const bool ok = rowok && (gw >= 0);
            float v0 = ok ? xb[(size_t)(ci4 * 4 + 0) * NH * NW + gw] : 0.0f;
            float v1 = ok ? xb[(size_t)(ci4 * 4 + 1) * NH * NW + gw] : 0.0f;
            float v2 = ok ? xb[(size_t)(ci4 * 4 + 2) * NH * NW + gw] : 0.0f;
            float v3 = ok ? xb[(size_t)(ci4 * 4 + 3) * NH * NW + gw] : 0.0f;
            bf16x4 pk = { f2bf(v0), f2bf(v1), f2bf(v2), f2bf(v3) };
            const int g  = ci4 >> 1;
            const int gp = g ^ ((wl >> 3) & 7);
            *(bf16x4*)&xs[(r * 66 + wl) * 72 + gp * 8 + (ci4 & 1) * 4] = pk;
        }
        if (s < 32) {
            const int wl  = 64 + (s & 1);
            const int ci4 = s >> 1;
            const int gw  = w0 - 1 + wl;
            const bool ok = rowok && (gw < NW);
            float v0 = ok ? xb[(size_t)(ci4 * 4 + 0) * NH * NW + gw] : 0.0f;
            float v1 = ok ? xb[(size_t)(ci4 * 4 + 1) * NH * NW + gw] : 0.0f;
            float v2 = ok ? xb[(size_t)(ci4 * 4 + 2) * NH * NW + gw] : 0.0f;
            float v3 = ok ? xb[(size_t)(ci4 * 4 + 3) * NH * NW + gw] : 0.0f;
            bf16x4 pk = { f2bf(v0), f2bf(v1), f2bf(v2), f2bf(v3) };
            const int g  = ci4 >> 1;
            const int gp = g ^ ((wl >> 3) & 7);
            *(bf16x4*)&xs[(r * 66 + wl) * 72 + gp * 8 + (ci4 & 1) * 4] = pk;
        }
    }

    const int mt   = wave & 3;
    const int nh   = wave >> 2;
    const int n    = lane & 15;
    const int quad = lane >> 4;

    const __bf16* Ap = A + ((size_t)b * NC + mt * 16 + n) * NKDIM + quad * 8;
    bf16x8 afr[9][2];
    #pragma unroll
    for (int tap = 0; tap < 9; ++tap)
        #pragma unroll
        for (int ch = 0; ch < 2; ++ch)
            afr[tap][ch] = *(const bf16x8*)(Ap + tap * 64 + ch * 32);

    __syncthreads();

    f32x4 acc[4];
    #pragma unroll
    for (int nt = 0; nt < 4; ++nt) acc[nt] = (f32x4){0.f, 0.f, 0.f, 0.f};

    #pragma unroll
    for (int tap = 0; tap < 9; ++tap) {
        const int dh  = tap / 3;
        const int dw  = tap - dh * 3;
        const int row = nh + dh;
        #pragma unroll
        for (int ch = 0; ch < 2; ++ch) {
            const int g = ch * 4 + quad;
            #pragma unroll
            for (int nt = 0; nt < 4; ++nt) {
                const int wl = dw + nt * 16 + n;
                const int gp = g ^ ((wl >> 3) & 7);
                bf16x8 bfr = *(const bf16x8*)&xs[(row * 66 + wl) * 72 + gp * 8];
                acc[nt] = __builtin_amdgcn_mfma_f32_16x16x32_bf16(
                    afr[tap][ch], bfr, acc[nt], 0, 0, 0);
            }
        }
    }

    const int h = h0 + nh;
    float* ob = out + (size_t)b * NC * NH * NW + (size_t)h * NW + w0;
    #pragma unroll
    for (int reg = 0; reg < 4; ++reg) {
        const int co = mt * 16 + quad * 4 + reg;
        float* orow = ob + (size_t)co * NH * NW;
        #pragma unroll
        for (int nt = 0; nt < 4; ++nt) {
            orow[nt * 16 + n] = acc[nt][reg];
        }
    }
}

// ---------------------------------------------------------------------------
extern "C" void kernel_launch(void* const* d_in, const int* in_sizes, int n_in,
                              void* d_out, int out_size, void* d_ws, size_t ws_size,
                              hipStream_t stream) {
    const float* x   = (const float*)d_in[0];
    const float* DoT = (const float*)d_in[1];
    const float* W0  = (const float*)d_in[2];
    const float* W1  = (const float*)d_in[3];
    float* out = (float*)d_out;

    // Workspace layout: A (blended bf16 weights) then xt (NHWC bf16 x).
    const size_t A_BYTES  = (size_t)NB * NC * NKDIM * 2;          // 1,179,648
    const size_t XT_BYTES = (size_t)NB * NH * NW * NC * 2;        // 75,497,472
    __bf16* A  = (__bf16*)d_ws;
    __bf16* xt = (__bf16*)((char*)d_ws + A_BYTES);

    blend_kernel<<<dim3((NB * NC * NKDIM) / 256), 256, 0, stream>>>(W0, W1, DoT, A);

    if (ws_size >= A_BYTES + XT_BYTES) {
        nhwc_cvt_kernel<<<dim3(NW / 64, NH, NB), dim3(256), 0, stream>>>(x, xt);
        conv_nhwc_kernel<<<dim3(NW / 64, NH / 2, NB), dim3(512), 0, stream>>>(xt, A, out);
    } else {
        conv_nchw_kernel<<<dim3(NW / 64, NH / 2, NB), dim3(512), 0, stream>>>(x, A, out);
    }
}